// Round 1
// baseline (2078.998 us; speedup 1.0000x reference)
//
#include <hip/hip_runtime.h>

// Fused RNN scan: h_{t+1} = tanh(W_ih x_t + b_ih + b_hh + W_hh h_t)
// 16 blocks (b-tile 16) x 512 threads (8 waves = 8 j-tiles of 16).
// Per step: 6x mfma_f32_16x16x32_f16 (K = 64 x-part + 128 h-part),
// h/x exchanged via double-buffered XOR-swizzled LDS, one raw s_barrier/step.
// x streamed from global with a depth-3 register prefetch ring (covers HBM latency)
// and cooperatively staged to LDS as fp16.

#define SEQ   4096
#define BATCH 256
#define DIN   64
#define DH    128

typedef _Float16 half8  __attribute__((ext_vector_type(8)));
typedef _Float16 half4v __attribute__((ext_vector_type(4)));
typedef _Float16 half2v __attribute__((ext_vector_type(2)));
typedef float    f32x4  __attribute__((ext_vector_type(4)));
typedef float    f32x2  __attribute__((ext_vector_type(2)));

// tanh(x) = 1 - 2/(1 + e^{2x}); e^{2x} = exp2(x * 2*log2(e)). Overflow-free for all finite x.
__device__ __forceinline__ float fast_tanh(float v) {
    float e = __builtin_amdgcn_exp2f(v * 2.88539008177792681472f);
    return 1.0f - 2.0f * __builtin_amdgcn_rcpf(e + 1.0f);
}

// h LDS row = 256 B = 16 chunks of 16 B; XOR chunk index with b (4 bits) -> conflict-optimal b128 reads.
__device__ __forceinline__ int hoff(int b, int chunk, int lo) {
    return b * 256 + ((chunk ^ b) << 4) + lo;
}
// x LDS row = 128 B = 8 chunks of 16 B; XOR with b&7.
__device__ __forceinline__ int xoff_lds(int b, int chunk, int lo) {
    return b * 128 + (((chunk ^ (b & 7)) << 4) + lo);
}

__launch_bounds__(512, 1)
__global__ void rnn_fused_scan(const float* __restrict__ x,     // [SEQ][BATCH][DIN]
                               const float* __restrict__ Wih,   // [DH][DIN]
                               const float* __restrict__ bih,   // [DH]
                               const float* __restrict__ Whh,   // [DH][DH]
                               const float* __restrict__ bhh,   // [DH]
                               float* __restrict__ out)         // [BATCH][DH]
{
    __shared__ __align__(16) char lds[12288];
    char* hbuf = lds;          // 2 x [16][128] f16, 4096 B each
    char* xbuf = lds + 8192;   // 2 x [16][64]  f16, 2048 B each

    const int tid   = threadIdx.x;
    const int wave  = tid >> 6;
    const int lane  = tid & 63;
    const int lb    = lane & 15;   // A: m-row ownership / B: n-col (=b) / C: col (=b)
    const int lg    = lane >> 4;   // k-group for A/B, row-group for C
    const int bbase = blockIdx.x << 4;
    const int jbase = wave << 4;

    // ---- persistent A-frags: W_hh (K=128 -> 4 frags), W_ih (K=64 -> 2 frags), as fp16 ----
    half8 Ahh[4], Aih[2];
    #pragma unroll
    for (int kt = 0; kt < 4; ++kt) {
        const float* wr = Whh + (jbase + lb) * DH + kt * 32 + lg * 8;
        half8 f;
        #pragma unroll
        for (int i = 0; i < 8; ++i) f[i] = (_Float16)wr[i];
        Ahh[kt] = f;
    }
    #pragma unroll
    for (int kt = 0; kt < 2; ++kt) {
        const float* wr = Wih + (jbase + lb) * DIN + kt * 32 + lg * 8;
        half8 f;
        #pragma unroll
        for (int i = 0; i < 8; ++i) f[i] = (_Float16)wr[i];
        Aih[kt] = f;
    }
    // bias in C/D layout: j = jbase + lg*4 + r (same for every b-col)
    f32x4 bias;
    #pragma unroll
    for (int r = 0; r < 4; ++r) {
        int j = jbase + lg * 4 + r;
        bias[r] = bih[j] + bhh[j];
    }

    // ---- x cooperative staging: thread -> 2 consecutive f32 of x[t][bbase+bx][kx..kx+1] ----
    const int bx = tid >> 5;          // 0..15
    const int kx = (tid & 31) << 1;   // 0,2,..,62
    const float* xlane = x + (size_t)(bbase + bx) * DIN + kx;
    const int XSTEP = BATCH * DIN;    // 16384 f32 per timestep

    // prologue: x[0] staged now; x[1..3] into the register ring
    f32x2 r0  = *(const f32x2*)(xlane + 0 * (size_t)XSTEP);
    f32x2 rx0 = *(const f32x2*)(xlane + 1 * (size_t)XSTEP);
    f32x2 rx1 = *(const f32x2*)(xlane + 2 * (size_t)XSTEP);
    f32x2 rx2 = *(const f32x2*)(xlane + 3 * (size_t)XSTEP);
    {
        half2v p; p[0] = (_Float16)r0[0]; p[1] = (_Float16)r0[1];
        *(half2v*)(xbuf + xoff_lds(bx, kx >> 3, (kx & 7) * 2)) = p;
    }
    const float* xload = xlane + 4 * (size_t)XSTEP;   // points at x[min(t+4, SEQ-1)]

    half8 hf0, hf1, hf2, hf3, xf0, xf1;
    {
        half8 z;
        #pragma unroll
        for (int i = 0; i < 8; ++i) z[i] = (_Float16)0.0f;
        hf0 = hf1 = hf2 = hf3 = z;   // h_0 = 0
    }

    asm volatile("s_waitcnt lgkmcnt(0)" ::: "memory");
    __builtin_amdgcn_s_barrier();
    asm volatile("" ::: "memory");
    xf0 = *(const half8*)(xbuf + xoff_lds(lb, 0 * 4 + lg, 0));
    xf1 = *(const half8*)(xbuf + xoff_lds(lb, 1 * 4 + lg, 0));

    #pragma unroll 2
    for (int t = 0; t < SEQ - 1; ++t) {
        // z = b + W_ih x_t + W_hh h_t   (f32 accumulate; bias frag feeds C of first MFMA)
        f32x4 acc;
        acc = __builtin_amdgcn_mfma_f32_16x16x32_f16(Aih[0], xf0, bias, 0, 0, 0);
        acc = __builtin_amdgcn_mfma_f32_16x16x32_f16(Aih[1], xf1, acc,  0, 0, 0);
        acc = __builtin_amdgcn_mfma_f32_16x16x32_f16(Ahh[0], hf0, acc,  0, 0, 0);
        acc = __builtin_amdgcn_mfma_f32_16x16x32_f16(Ahh[1], hf1, acc,  0, 0, 0);
        acc = __builtin_amdgcn_mfma_f32_16x16x32_f16(Ahh[2], hf2, acc,  0, 0, 0);
        acc = __builtin_amdgcn_mfma_f32_16x16x32_f16(Ahh[3], hf3, acc,  0, 0, 0);

        const int nb = (t + 1) & 1;   // unroll-2 makes this a compile-time constant

        // stage x[t+1] (rx0) into xbuf[nb]; refill ring with x[t+4]
        {
            half2v p; p[0] = (_Float16)rx0[0]; p[1] = (_Float16)rx0[1];
            *(half2v*)(xbuf + nb * 2048 + xoff_lds(bx, kx >> 3, (kx & 7) * 2)) = p;
        }
        rx0 = rx1; rx1 = rx2;
        rx2 = *(const f32x2*)xload;
        if (t + 5 < SEQ) xload += XSTEP;   // clamp: re-load last row near the tail (never consumed)

        // h_{t+1} = tanh(z) -> fp16 -> LDS
        f32x4 hv;
        #pragma unroll
        for (int r = 0; r < 4; ++r) hv[r] = fast_tanh(acc[r]);
        {
            half4v p;
            #pragma unroll
            for (int r = 0; r < 4; ++r) p[r] = (_Float16)hv[r];
            *(half4v*)(hbuf + nb * 4096 + hoff(lb, (wave << 1) + (lg >> 1), (lg & 1) * 8)) = p;
        }

        // exchange: own LDS writes done -> barrier -> everyone's writes visible
        asm volatile("s_waitcnt lgkmcnt(0)" ::: "memory");
        __builtin_amdgcn_s_barrier();
        asm volatile("" ::: "memory");

        hf0 = *(const half8*)(hbuf + nb * 4096 + hoff(lb, 0 * 4 + lg, 0));
        hf1 = *(const half8*)(hbuf + nb * 4096 + hoff(lb, 1 * 4 + lg, 0));
        hf2 = *(const half8*)(hbuf + nb * 4096 + hoff(lb, 2 * 4 + lg, 0));
        hf3 = *(const half8*)(hbuf + nb * 4096 + hoff(lb, 3 * 4 + lg, 0));
        xf0 = *(const half8*)(xbuf + nb * 2048 + xoff_lds(lb, 0 * 4 + lg, 0));
        xf1 = *(const half8*)(xbuf + nb * 2048 + xoff_lds(lb, 1 * 4 + lg, 0));
    }

    // epilogue: t = SEQ-1, produce h_final and store (f32, [BATCH][DH])
    {
        f32x4 acc;
        acc = __builtin_amdgcn_mfma_f32_16x16x32_f16(Aih[0], xf0, bias, 0, 0, 0);
        acc = __builtin_amdgcn_mfma_f32_16x16x32_f16(Aih[1], xf1, acc,  0, 0, 0);
        acc = __builtin_amdgcn_mfma_f32_16x16x32_f16(Ahh[0], hf0, acc,  0, 0, 0);
        acc = __builtin_amdgcn_mfma_f32_16x16x32_f16(Ahh[1], hf1, acc,  0, 0, 0);
        acc = __builtin_amdgcn_mfma_f32_16x16x32_f16(Ahh[2], hf2, acc,  0, 0, 0);
        acc = __builtin_amdgcn_mfma_f32_16x16x32_f16(Ahh[3], hf3, acc,  0, 0, 0);
        f32x4 res;
        #pragma unroll
        for (int r = 0; r < 4; ++r) res[r] = fast_tanh(acc[r]);
        *(f32x4*)(out + (size_t)(bbase + lb) * DH + jbase + (lg << 2)) = res;
    }
}

extern "C" void kernel_launch(void* const* d_in, const int* in_sizes, int n_in,
                              void* d_out, int out_size, void* d_ws, size_t ws_size,
                              hipStream_t stream) {
    const float* x   = (const float*)d_in[0];
    const float* Wih = (const float*)d_in[1];
    const float* bih = (const float*)d_in[2];
    const float* Whh = (const float*)d_in[3];
    const float* bhh = (const float*)d_in[4];
    float* out = (float*)d_out;
    rnn_fused_scan<<<16, 512, 0, stream>>>(x, Wih, bih, Whh, bhh, out);
}

// Round 2
// 1767.614 us; speedup vs baseline: 1.1762x; 1.1762x over previous
//
#include <hip/hip_runtime.h>

// Fused RNN scan: h_{t+1} = tanh(W_ih x_t + b_ih + b_hh + W_hh h_t)
// 16 blocks (b-tile 16) x 512 threads (8 waves = 8 j-tiles of 16).
// R2: dependency-chain split. Per step the critical path is now only
//   2 dependent hh-MFMAs (chain1: C-in = acc_ih precomputed last step;
//   chain2: C-in = 0) + add + tanh + pack + ds_write + barrier + ds_read.
// The ih MFMAs (x-projection) for step t+1 are issued right after the
// barrier of step t, off the critical path.

#define SEQ   4096
#define BATCH 256
#define DIN   64
#define DH    128

typedef _Float16 half8  __attribute__((ext_vector_type(8)));
typedef _Float16 half4v __attribute__((ext_vector_type(4)));
typedef _Float16 half2v __attribute__((ext_vector_type(2)));
typedef float    f32x4  __attribute__((ext_vector_type(4)));
typedef float    f32x2  __attribute__((ext_vector_type(2)));

// tanh(x) = 1 - 2/(1 + e^{2x}); e^{2x} = exp2(x * 2*log2(e)). Overflow-free for all finite x.
__device__ __forceinline__ float fast_tanh(float v) {
    float e = __builtin_amdgcn_exp2f(v * 2.88539008177792681472f);
    return 1.0f - 2.0f * __builtin_amdgcn_rcpf(e + 1.0f);
}

// h LDS row = 256 B = 16 chunks of 16 B; XOR chunk index with b (4 bits) -> conflict-optimal b128 reads.
__device__ __forceinline__ int hoff(int b, int chunk, int lo) {
    return b * 256 + ((chunk ^ b) << 4) + lo;
}
// x LDS row = 128 B = 8 chunks of 16 B; XOR with b&7.
__device__ __forceinline__ int xoff_lds(int b, int chunk, int lo) {
    return b * 128 + (((chunk ^ (b & 7)) << 4) + lo);
}

__launch_bounds__(512, 1)
__global__ void rnn_fused_scan(const float* __restrict__ x,     // [SEQ][BATCH][DIN]
                               const float* __restrict__ Wih,   // [DH][DIN]
                               const float* __restrict__ bih,   // [DH]
                               const float* __restrict__ Whh,   // [DH][DH]
                               const float* __restrict__ bhh,   // [DH]
                               float* __restrict__ out)         // [BATCH][DH]
{
    __shared__ __align__(16) char lds[12288];
    char* hbuf = lds;          // 2 x [16][128] f16, 4096 B each
    char* xbuf = lds + 8192;   // 2 x [16][64]  f16, 2048 B each

    const int tid   = threadIdx.x;
    const int wave  = tid >> 6;
    const int lane  = tid & 63;
    const int lb    = lane & 15;   // A: m-row ownership / B: n-col (=b) / C: col (=b)
    const int lg    = lane >> 4;   // k-group for A/B, row-group for C
    const int bbase = blockIdx.x << 4;
    const int jbase = wave << 4;

    // ---- persistent A-frags: W_hh (K=128 -> 4 frags), W_ih (K=64 -> 2 frags), as fp16 ----
    half8 Ahh[4], Aih[2];
    #pragma unroll
    for (int kt = 0; kt < 4; ++kt) {
        const float* wr = Whh + (jbase + lb) * DH + kt * 32 + lg * 8;
        half8 f;
        #pragma unroll
        for (int i = 0; i < 8; ++i) f[i] = (_Float16)wr[i];
        Ahh[kt] = f;
    }
    #pragma unroll
    for (int kt = 0; kt < 2; ++kt) {
        const float* wr = Wih + (jbase + lb) * DIN + kt * 32 + lg * 8;
        half8 f;
        #pragma unroll
        for (int i = 0; i < 8; ++i) f[i] = (_Float16)wr[i];
        Aih[kt] = f;
    }
    // bias in C/D layout: j = jbase + lg*4 + r (same for every b-col)
    f32x4 bias;
    #pragma unroll
    for (int r = 0; r < 4; ++r) {
        int j = jbase + lg * 4 + r;
        bias[r] = bih[j] + bhh[j];
    }

    // ---- x cooperative staging: thread -> 2 consecutive f32 of x[t][bbase+bx][kx..kx+1] ----
    const int bx = tid >> 5;          // 0..15
    const int kx = (tid & 31) << 1;   // 0,2,..,62
    const float* xlane = x + (size_t)(bbase + bx) * DIN + kx;
    const int XSTEP = BATCH * DIN;    // 16384 f32 per timestep

    // prologue: x[0] staged now; x[1..3] into the register ring
    f32x2 r0  = *(const f32x2*)(xlane + 0 * (size_t)XSTEP);
    f32x2 rx0 = *(const f32x2*)(xlane + 1 * (size_t)XSTEP);
    f32x2 rx1 = *(const f32x2*)(xlane + 2 * (size_t)XSTEP);
    f32x2 rx2 = *(const f32x2*)(xlane + 3 * (size_t)XSTEP);
    {
        half2v p; p[0] = (_Float16)r0[0]; p[1] = (_Float16)r0[1];
        *(half2v*)(xbuf + xoff_lds(bx, kx >> 3, (kx & 7) * 2)) = p;
    }
    const float* xload = xlane + 4 * (size_t)XSTEP;

    half8 hf0, hf1, hf2, hf3, xf0, xf1;
    {
        half8 z;
        #pragma unroll
        for (int i = 0; i < 8; ++i) z[i] = (_Float16)0.0f;
        hf0 = hf1 = hf2 = hf3 = z;   // h_0 = 0
    }

    asm volatile("s_waitcnt lgkmcnt(0)" ::: "memory");
    __builtin_amdgcn_s_barrier();
    asm volatile("" ::: "memory");
    xf0 = *(const half8*)(xbuf + xoff_lds(lb, 0 * 4 + lg, 0));
    xf1 = *(const half8*)(xbuf + xoff_lds(lb, 1 * 4 + lg, 0));

    // acc_ih for step 0 (C-in of chain1 at the top of body 0)
    f32x4 acc_ih;
    acc_ih = __builtin_amdgcn_mfma_f32_16x16x32_f16(Aih[0], xf0, bias,   0, 0, 0);
    acc_ih = __builtin_amdgcn_mfma_f32_16x16x32_f16(Aih[1], xf1, acc_ih, 0, 0, 0);

    #pragma unroll 2
    for (int t = 0; t < SEQ - 1; ++t) {
        // two independent hh chains of depth 2 (chain1 carries acc_ih = Wih x_t + b)
        f32x4 zz = {0.0f, 0.0f, 0.0f, 0.0f};
        f32x4 acc1, acc2;
        acc1 = __builtin_amdgcn_mfma_f32_16x16x32_f16(Ahh[0], hf0, acc_ih, 0, 0, 0);
        acc2 = __builtin_amdgcn_mfma_f32_16x16x32_f16(Ahh[2], hf2, zz,     0, 0, 0);
        acc1 = __builtin_amdgcn_mfma_f32_16x16x32_f16(Ahh[1], hf1, acc1,   0, 0, 0);
        acc2 = __builtin_amdgcn_mfma_f32_16x16x32_f16(Ahh[3], hf3, acc2,   0, 0, 0);

        const int nb = (t + 1) & 1;   // unroll-2 makes this a compile-time constant

        // stage x[t+1] (rx0) into xbuf[nb]; refill ring with x[t+4]
        {
            half2v p; p[0] = (_Float16)rx0[0]; p[1] = (_Float16)rx0[1];
            *(half2v*)(xbuf + nb * 2048 + xoff_lds(bx, kx >> 3, (kx & 7) * 2)) = p;
        }
        rx0 = rx1; rx1 = rx2;
        rx2 = *(const f32x2*)xload;
        if (t + 5 < SEQ) xload += XSTEP;

        // h_{t+1} = tanh(acc1 + acc2) -> fp16 -> LDS
        f32x4 hv;
        #pragma unroll
        for (int r = 0; r < 4; ++r) hv[r] = fast_tanh(acc1[r] + acc2[r]);
        {
            half4v p;
            #pragma unroll
            for (int r = 0; r < 4; ++r) p[r] = (_Float16)hv[r];
            *(half4v*)(hbuf + nb * 4096 + hoff(lb, (wave << 1) + (lg >> 1), (lg & 1) * 8)) = p;
        }

        // exchange: own LDS writes done -> barrier -> everyone's writes visible
        asm volatile("s_waitcnt lgkmcnt(0)" ::: "memory");
        __builtin_amdgcn_s_barrier();
        asm volatile("" ::: "memory");

        // chain-head frags first
        hf0 = *(const half8*)(hbuf + nb * 4096 + hoff(lb, 0 * 4 + lg, 0));
        hf2 = *(const half8*)(hbuf + nb * 4096 + hoff(lb, 2 * 4 + lg, 0));
        hf1 = *(const half8*)(hbuf + nb * 4096 + hoff(lb, 1 * 4 + lg, 0));
        hf3 = *(const half8*)(hbuf + nb * 4096 + hoff(lb, 3 * 4 + lg, 0));
        xf0 = *(const half8*)(xbuf + nb * 2048 + xoff_lds(lb, 0 * 4 + lg, 0));
        xf1 = *(const half8*)(xbuf + nb * 2048 + xoff_lds(lb, 1 * 4 + lg, 0));

        // ih projection for step t+1 — off the critical path (consumed as C-in next body)
        acc_ih = __builtin_amdgcn_mfma_f32_16x16x32_f16(Aih[0], xf0, bias,   0, 0, 0);
        acc_ih = __builtin_amdgcn_mfma_f32_16x16x32_f16(Aih[1], xf1, acc_ih, 0, 0, 0);
    }

    // epilogue: t = SEQ-1, produce h_final and store (f32, [BATCH][DH])
    {
        f32x4 zz = {0.0f, 0.0f, 0.0f, 0.0f};
        f32x4 acc1, acc2;
        acc1 = __builtin_amdgcn_mfma_f32_16x16x32_f16(Ahh[0], hf0, acc_ih, 0, 0, 0);
        acc2 = __builtin_amdgcn_mfma_f32_16x16x32_f16(Ahh[2], hf2, zz,     0, 0, 0);
        acc1 = __builtin_amdgcn_mfma_f32_16x16x32_f16(Ahh[1], hf1, acc1,   0, 0, 0);
        acc2 = __builtin_amdgcn_mfma_f32_16x16x32_f16(Ahh[3], hf3, acc2,   0, 0, 0);
        f32x4 res;
        #pragma unroll
        for (int r = 0; r < 4; ++r) res[r] = fast_tanh(acc1[r] + acc2[r]);
        *(f32x4*)(out + (size_t)(bbase + lb) * DH + jbase + (lg << 2)) = res;
    }
}

extern "C" void kernel_launch(void* const* d_in, const int* in_sizes, int n_in,
                              void* d_out, int out_size, void* d_ws, size_t ws_size,
                              hipStream_t stream) {
    const float* x   = (const float*)d_in[0];
    const float* Wih = (const float*)d_in[1];
    const float* bih = (const float*)d_in[2];
    const float* Whh = (const float*)d_in[3];
    const float* bhh = (const float*)d_in[4];
    float* out = (float*)d_out;
    rnn_fused_scan<<<16, 512, 0, stream>>>(x, Wih, bih, Whh, bhh, out);
}